// Round 17
// baseline (223.763 us; speedup 1.0000x reference)
//
#include <hip/hip_runtime.h>
#include <hip/hip_bf16.h>

// Linear attention (Shen 2018), B=2, N=16384, D=512, H=8, DK=64.
// Round 17 = R16 plus:
//   - two-stage parallel reduce (16-block reduce was a serial tail: 16 CUs
//     reading 33MB at single-CU bandwidth). stage1: 256 blocks sum 8 groups
//     each; stage2: 16 blocks finish + normalize.
//   - phase1 E^T via in-register shuffles (8 shfl + 4 selects from the acc
//     pk2 pairs) instead of the ET LDS round-trip: LDS 48->40KB, fewer
//     epilogue LDS ops. V^T keeps LDS (cross-wave e-blocks).
// phase3/wcvt/mbigT and all staging pipelines byte-identical to R16
// (verified, absmax 1.9e-5).

using u16 = unsigned short;
typedef __attribute__((ext_vector_type(8))) short bf16x8;
typedef __attribute__((ext_vector_type(4))) float f32x4;

#define D_MODEL 512
#define SEQ 16384

// SWZ fragment layout for a 512x512 bf16 operand consumed as mfma_16x16x32
// row-panels: element (col,k) at cb16=col>>4, lc=col&15, ksm=k>>5, g=(k>>3)&3,
// j=k&7, lane=g*16+lc:  idx = cb16*8192 + ksm*512 + lane*8 + j   (u16 units)

// ---- ws layout (bytes) ----
#define PART_OFF 0u            // f32 [16 bh][128 grp][64 e][64 d] = 33,554,432
#define SUMS_OFF 33554432u     // f32 [16 bh][128 grp][64 d]       = 524,288
#define CTX_OFF  34078720u     // f32 [16][64 d][64 e]             = 262,144
#define WTKS_OFF 34340864u     // bf16 swz 512x512 = 524,288
#define WTVS_OFF 34865152u
#define WTQS_OFF 35389440u
#define MTS_OFF  35913728u     // bf16 swz [2]x512x512 = 1,048,576
#define PART2_OFF 36962304u    // f32 [16 bh][16 seg][4096] = 4,194,304
#define SUMS2_OFF 41156608u    // f32 [16 bh][16 seg][64]   = 65,536
#define WS_NEEDED 41222144u

__device__ __forceinline__ float bf2f(u16 u) {
  union { unsigned int i; float f; } x; x.i = ((unsigned int)u) << 16; return x.f;
}
__device__ __forceinline__ u16 f2bf(float f) {
  union { float ff; unsigned int i; } x; x.ff = f;
  unsigned int r = x.i + 0x7fffu + ((x.i >> 16) & 1u);  // RNE
  return (u16)(r >> 16);
}
__device__ __forceinline__ unsigned int pk2(float lo, float hi) {
  union { __hip_bfloat162 h; unsigned int u; } x;
  x.h = __float22bfloat162_rn(float2{lo, hi});
  return x.u;
}
__device__ __forceinline__ bf16x8 ldsrd(const u16* base, int row, int rowbytes,
                                        int kbyte, int mask) {
  return *(const bf16x8*)((const char*)base + row * rowbytes + (kbyte ^ ((row & mask) << 4)));
}
// LDS-only barrier (no vmcnt drain): safe because at every barrier the only
// in-flight vmem ops are register-destined loads or fire-and-forget stores.
__device__ __forceinline__ void bar_lgkm() {
  asm volatile("s_waitcnt lgkmcnt(0)" ::: "memory");
  __builtin_amdgcn_sched_barrier(0);
  __builtin_amdgcn_s_barrier();
  __builtin_amdgcn_sched_barrier(0);
}

// ------- transpose+convert W -> swizzled fragment-order bf16 panels ---------
__launch_bounds__(256)
__global__ void wcvt_kernel(const float* __restrict__ Wk, const float* __restrict__ Wv,
                            const float* __restrict__ Wq, u16* __restrict__ WTks,
                            u16* __restrict__ WTvs, u16* __restrict__ WTqs) {
  const float* in = blockIdx.z == 0 ? Wk : (blockIdx.z == 1 ? Wv : Wq);
  u16* out = blockIdx.z == 0 ? WTks : (blockIdx.z == 1 ? WTvs : WTqs);
  __shared__ float S[64][65];  // [k][col]
  const int t = threadIdx.x;
  const int k0 = blockIdx.y << 6, c0 = blockIdx.x << 6;
#pragma unroll
  for (int ii = 0; ii < 4; ++ii) {
    const int idx = t + ii * 256;
    const int r = idx >> 4, c4 = (idx & 15) << 2;
    const float4 v = *(const float4*)(in + (k0 + r) * D_MODEL + c0 + c4);
    S[r][c4] = v.x; S[r][c4 + 1] = v.y; S[r][c4 + 2] = v.z; S[r][c4 + 3] = v.w;
  }
  __syncthreads();
#pragma unroll
  for (int it = 0; it < 2; ++it) {
    const int fi = it * 256 + t;             // 0..511
    const int cb_loc = fi >> 7;              // 0..3
    const int ksm_loc = (fi >> 6) & 1;       // 0..1
    const int lane = fi & 63;
    const int col_loc = cb_loc * 16 + (lane & 15);
    const int kl0 = ksm_loc * 32 + (lane >> 4) * 8;
    union { bf16x8 v; u16 e[8]; } o;
#pragma unroll
    for (int jj = 0; jj < 8; ++jj) o.e[jj] = f2bf(S[kl0 + jj][col_loc]);
    const int cb16 = blockIdx.x * 4 + cb_loc;
    const int ksm = blockIdx.y * 2 + ksm_loc;
    *(bf16x8*)(out + cb16 * 8192 + ksm * 512 + lane * 8) = o.v;
  }
}

// ---------------- phase 1: [32][128] slices, depth-3 prefetch ---------------
// grid 1024: xc=f&7 (XCD), k=f>>3: rowgroup = xc*32 + (k>>2) in [0,256),
// hp = k&3. Block: 8 waves = 2 heads (hloc=w>>2) x 4 col-quarters (cq=w&3);
// 16 slices of [32 rows][128 k] (4 chunks x 4), double-buffered LDS,
// 3 rotating register prefetch sets. E^T fragment built in-register.
__launch_bounds__(512, 2)
__global__ void phase1_kernel(const float* __restrict__ key, const float* __restrict__ value,
                              const u16* __restrict__ WTks, const u16* __restrict__ WTvs,
                              const float* __restrict__ bkp, const float* __restrict__ bvp,
                              float* __restrict__ part, float* __restrict__ sums) {
  __shared__ __align__(16) u16 smem[20480];  // 40KB
  u16* KA = smem;            // [2 buf][32 n][128 k], rows 256B, swz mask 7 (16KB)
  u16* VA = smem + 8192;     // (16KB)
  u16* VT = smem + 16384;    // [2 hloc][64 e][32 n], rows 64B, swz mask 3 (8KB)
  const int t = threadIdx.x;
  const int lane = t & 63, w = t >> 6;
  const int g = lane >> 4, lc = lane & 15;
  const int f = blockIdx.x;
  const int xc = f & 7, kk2 = f >> 3;
  const int rowgroup = xc * 32 + (kk2 >> 2);   // 0..255
  const int hp = kk2 & 3;
  const int hloc = w >> 2, cq = w & 3;
  const int h = hp * 2 + hloc;
  const int dl = cq * 16 + lc;
  const int b = rowgroup >> 7, grpl = rowgroup & 127;
  const int bh = b * 8 + h;
  u16* VTh = VT + hloc * 2048;
  const u16* wtkb = WTks + (h * 4 + cq) * 8192;
  const u16* wtvb = WTvs + (h * 4 + cq) * 8192;
  const float bbk = bkp[h * 64 + dl];
  const float bbv = bvp[h * 64 + dl];
  const int sr = t >> 4;                 // staging row 0..31
  const int sc = t & 15;                 // staging col-octet (8 f32)
  const int swoff = sr * 256 + ((sc * 16) ^ ((sr & 7) << 4));

  f32x4 pacc[4];
#pragma unroll
  for (int em = 0; em < 4; ++em) pacc[em] = (f32x4){0.f, 0.f, 0.f, 0.f};
  float sp = 0.f;
  f32x4 aK0 = (f32x4){0.f,0.f,0.f,0.f}, aK1 = aK0, aV0 = aK0, aV1 = aK0;

  float4 kreg[3][2], vreg[3][2];   // depth-3 rotating prefetch sets
  auto LOADSL = [&](int set, int gs) {    // called with compile-time args
    const int row = (rowgroup * 4 + (gs >> 2)) * 32 + sr;
    const float* kp = key + (size_t)row * D_MODEL + (gs & 3) * 128 + sc * 8;
    kreg[set][0] = *(const float4*)kp; kreg[set][1] = *(const float4*)(kp + 4);
    const float* vp = value + (size_t)row * D_MODEL + (gs & 3) * 128 + sc * 8;
    vreg[set][0] = *(const float4*)vp; vreg[set][1] = *(const float4*)(vp + 4);
  };
  auto WRITESL = [&](int set, int buf) {
    const float4 k0 = kreg[set][0], k1 = kreg[set][1];
    uint4 wk; wk.x = pk2(k0.x, k0.y); wk.y = pk2(k0.z, k0.w);
    wk.z = pk2(k1.x, k1.y); wk.w = pk2(k1.z, k1.w);
    *(uint4*)((char*)KA + buf * 8192 + swoff) = wk;
    const float4 v0 = vreg[set][0], v1 = vreg[set][1];
    uint4 wv; wv.x = pk2(v0.x, v0.y); wv.y = pk2(v0.z, v0.w);
    wv.z = pk2(v1.x, v1.y); wv.w = pk2(v1.z, v1.w);
    *(uint4*)((char*)VA + buf * 8192 + swoff) = wv;
  };

  // prologue: slices 0,1,2 in flight; slice 0 -> buf0
  LOADSL(0, 0);
  LOADSL(1, 1);
  LOADSL(2, 2);
  WRITESL(0, 0);
  bar_lgkm();

#pragma unroll
  for (int gs = 0; gs < 16; ++gs) {
    // ---- B-frag panels for this slice (L2), issued first ----
    bf16x8 bK[4], bV[4];
#pragma unroll
    for (int j = 0; j < 4; ++j) {
      const int ksm = (gs & 3) * 4 + j;
      bK[j] = *(const bf16x8*)(wtkb + ksm * 512 + lane * 8);
      bV[j] = *(const bf16x8*)(wtvb + ksm * 512 + lane * 8);
    }
    // ---- write slice gs+1 (loaded 2 slice-periods ago: no vmcnt stall) ----
    if (gs + 1 < 16) WRITESL((gs + 1) % 3, (gs + 1) & 1);
    // ---- refill freed set with slice gs+3 ----
    if (gs + 3 < 16) LOADSL(gs % 3, gs + 3);
    const u16* bufK = KA + (gs & 1) * 4096;
    const u16* bufV = VA + (gs & 1) * 4096;
    // ---- 4 k-steps of MFMA on slice gs ----
#pragma unroll
    for (int ksl = 0; ksl < 4; ++ksl) {
      const int kb = ksl * 64 + g * 16;
      bf16x8 a0 = ldsrd(bufK, lc, 256, kb, 7);
      bf16x8 a1 = ldsrd(bufK, 16 + lc, 256, kb, 7);
      aK0 = __builtin_amdgcn_mfma_f32_16x16x32_bf16(a0, bK[ksl], aK0, 0, 0, 0);
      aK1 = __builtin_amdgcn_mfma_f32_16x16x32_bf16(a1, bK[ksl], aK1, 0, 0, 0);
      bf16x8 c0 = ldsrd(bufV, lc, 256, kb, 7);
      bf16x8 c1 = ldsrd(bufV, 16 + lc, 256, kb, 7);
      aV0 = __builtin_amdgcn_mfma_f32_16x16x32_bf16(c0, bV[ksl], aV0, 0, 0, 0);
      aV1 = __builtin_amdgcn_mfma_f32_16x16x32_bf16(c1, bV[ksl], aV1, 0, 0, 0);
    }
    if ((gs & 3) == 3) {
      // ---- chunk epilogue ----
      // E: exp + colsum (acc layout: d = dl, n = g*4+r (aK0) / 16+g*4+r (aK1))
#pragma unroll
      for (int r = 0; r < 4; ++r) { aK0[r] = __expf(aK0[r] + bbk); sp += aK0[r]; }
#pragma unroll
      for (int r = 0; r < 4; ++r) { aK1[r] = __expf(aK1[r] + bbk); sp += aK1[r]; }
      // E^T A-frag IN-REGISTER (replaces ET LDS round-trip):
      // target lane (G=g, d=lc): word m = (G<2 ? p{m&1} : p{2+(m&1)})
      // from lane ((2G+(m>>1))&3)*16 + lc.  p0..p3 = packed acc pairs.
      union { bf16x8 v; unsigned int u[4]; } paf;
      {
        const unsigned int p0 = pk2(aK0[0], aK0[1]);
        const unsigned int p1 = pk2(aK0[2], aK0[3]);
        const unsigned int p2 = pk2(aK1[0], aK1[1]);
        const unsigned int p3 = pk2(aK1[2], aK1[3]);
        const int srcA = (((2 * g) & 3) << 4) + lc;
        const int srcB = (((2 * g + 1) & 3) << 4) + lc;
        const unsigned int w0a = (unsigned)__shfl((int)p0, srcA);
        const unsigned int w0b = (unsigned)__shfl((int)p2, srcA);
        const unsigned int w1a = (unsigned)__shfl((int)p1, srcA);
        const unsigned int w1b = (unsigned)__shfl((int)p3, srcA);
        const unsigned int w2a = (unsigned)__shfl((int)p0, srcB);
        const unsigned int w2b = (unsigned)__shfl((int)p2, srcB);
        const unsigned int w3a = (unsigned)__shfl((int)p1, srcB);
        const unsigned int w3b = (unsigned)__shfl((int)p3, srcB);
        const bool lo = (g < 2);
        paf.u[0] = lo ? w0a : w0b;
        paf.u[1] = lo ? w1a : w1b;
        paf.u[2] = lo ? w2a : w2b;
        paf.u[3] = lo ? w3a : w3b;
      }
      // V: bias, V^T strip -> VTh (cross-wave e-blocks still need LDS)
      *(uint2*)((char*)VTh + dl * 64 + ((g * 8) ^ ((dl & 3) << 4))) =
          make_uint2(pk2(aV0[0] + bbv, aV0[1] + bbv), pk2(aV0[2] + bbv, aV0[3] + bbv));
      *(uint2*)((char*)VTh + dl * 64 + ((32 + g * 8) ^ ((dl & 3) << 4))) =
          make_uint2(pk2(aV1[0] + bbv, aV1[1] + bbv), pk2(aV1[2] + bbv, aV1[3] + bbv));
      bar_lgkm();  // VT complete across the head's 4 waves
      {
#pragma unroll
        for (int em = 0; em < 4; ++em) {
          bf16x8 pbf = ldsrd(VTh, em * 16 + lc, 64, g * 16, 3);
          pacc[em] = __builtin_amdgcn_mfma_f32_16x16x32_bf16(paf.v, pbf, pacc[em], 0, 0, 0);
        }
      }
      aK0 = (f32x4){0.f,0.f,0.f,0.f}; aK1 = aK0; aV0 = aK0; aV1 = aK0;
    }
    bar_lgkm();  // slice gs+1 visible; buf (gs&1) reads done; epilogue's
                 // VT reads done before the next chunk's VT writes.
  }

  // ---- one store per block: f32 partials [e][d] + colsums ----
  float* pp = part + (size_t)(bh * 128 + grpl) * 4096;
#pragma unroll
  for (int em = 0; em < 4; ++em)
    *(f32x4*)(pp + (em * 16 + lc) * 64 + cq * 16 + g * 4) = pacc[em];
  sp += __shfl_xor(sp, 16); sp += __shfl_xor(sp, 32);
  if (g == 0) sums[(size_t)(bh * 128 + grpl) * 64 + dl] = sp;
}

// ------- phase 2a: stage-1 reduce (256 blocks: 16 seg x 16 bh) --------------
__launch_bounds__(256)
__global__ void reduce1_kernel(const float* __restrict__ part, const float* __restrict__ sums,
                               float* __restrict__ part2, float* __restrict__ sums2) {
  const int seg = blockIdx.x, bh = blockIdx.y;
  const int t = threadIdx.x;
  float4 A0 = {0,0,0,0}, A1 = {0,0,0,0}, A2 = {0,0,0,0}, A3 = {0,0,0,0};
  const float* pb = part + (size_t)(bh * 128 + seg * 8) * 4096;
#pragma unroll
  for (int gp = 0; gp < 8; ++gp) {
    const float4* q = (const float4*)(pb + gp * 4096 + t * 16);
    const float4 q0 = q[0], q1 = q[1], q2 = q[2], q3 = q[3];
    A0.x += q0.x; A0.y += q0.y; A0.z += q0.z; A0.w += q0.w;
    A1.x += q1.x; A1.y += q1.y; A1.z += q1.z; A1.w += q1.w;
    A2.x += q2.x; A2.y += q2.y; A2.z += q2.z; A2.w += q2.w;
    A3.x += q3.x; A3.y += q3.y; A3.z += q3.z; A3.w += q3.w;
  }
  float4* o = (float4*)(part2 + (size_t)(bh * 16 + seg) * 4096 + t * 16);
  o[0] = A0; o[1] = A1; o[2] = A2; o[3] = A3;
  if (t < 64) {
    const float* sb = sums + (size_t)(bh * 128 + seg * 8) * 64 + t;
    float s = 0.f;
#pragma unroll
    for (int gp = 0; gp < 8; ++gp) s += sb[gp * 64];
    sums2[(size_t)(bh * 16 + seg) * 64 + t] = s;
  }
}

// ------- phase 2b: stage-2 reduce + normalize -> ctx[d][e] ------------------
__launch_bounds__(256)
__global__ void reduce2_kernel(const float* __restrict__ part2, const float* __restrict__ sums2,
                               float* __restrict__ ctx) {
  __shared__ float den[64];
  const int bh = blockIdx.x;
  const int t = threadIdx.x;
  if (t < 64) {
    const float* sb = sums2 + (size_t)bh * 16 * 64 + t;
    float s = 0.f;
#pragma unroll
    for (int seg = 0; seg < 16; ++seg) s += sb[seg * 64];
    den[t] = s;
  }
  float4 A0 = {0,0,0,0}, A1 = {0,0,0,0}, A2 = {0,0,0,0}, A3 = {0,0,0,0};
  const float* pb = part2 + (size_t)bh * 16 * 4096;
#pragma unroll
  for (int seg = 0; seg < 16; ++seg) {
    const float4* q = (const float4*)(pb + seg * 4096 + t * 16);
    const float4 q0 = q[0], q1 = q[1], q2 = q[2], q3 = q[3];
    A0.x += q0.x; A0.y += q0.y; A0.z += q0.z; A0.w += q0.w;
    A1.x += q1.x; A1.y += q1.y; A1.z += q1.z; A1.w += q1.w;
    A2.x += q2.x; A2.y += q2.y; A2.z += q2.z; A2.w += q2.w;
    A3.x += q3.x; A3.y += q3.y; A3.z += q3.z; A3.w += q3.w;
  }
  __syncthreads();
  // positions p = t*16 + i in [e][d]: e = t>>2, d = (t&3)*16 + i
  const int e = t >> 2, d0 = (t & 3) * 16;
  float* cb = ctx + (size_t)bh * 4096 + e;
  const float r0[4] = {A0.x, A0.y, A0.z, A0.w};
  const float r1[4] = {A1.x, A1.y, A1.z, A1.w};
  const float r2[4] = {A2.x, A2.y, A2.z, A2.w};
  const float r3[4] = {A3.x, A3.y, A3.z, A3.w};
#pragma unroll
  for (int i = 0; i < 4; ++i) cb[(d0 + i) * 64] = r0[i] / den[d0 + i];
#pragma unroll
  for (int i = 0; i < 4; ++i) cb[(d0 + 4 + i) * 64] = r1[i] / den[d0 + 4 + i];
#pragma unroll
  for (int i = 0; i < 4; ++i) cb[(d0 + 8 + i) * 64] = r2[i] / den[d0 + 8 + i];
#pragma unroll
  for (int i = 0; i < 4; ++i) cb[(d0 + 12 + i) * 64] = r3[i] / den[d0 + 12 + i];
}

// -------- MTs (swizzled) = (ctx_h @ Wo_h)^T per batch -----------------------
__launch_bounds__(256)
__global__ void mbigT_kernel(const float* __restrict__ ctx, const float* __restrict__ Wo,
                             u16* __restrict__ MTs) {
  __shared__ float Clds[64][65];
  __shared__ float Wlds2[64][64];
  const int t = threadIdx.x;
  const int tx = t & 15, ty = t >> 4;
  const int cc = blockIdx.x;
  const int bh = blockIdx.y;
  const int b = bh >> 3, h = bh & 7;
  const float* ch = ctx + bh * 4096;
  for (int i4 = t; i4 < 1024; i4 += 256) {
    const int r = i4 >> 4, c = (i4 & 15) << 2;
    const float4 v = *(const float4*)(ch + (r << 6) + c);
    Clds[r][c] = v.x; Clds[r][c + 1] = v.y; Clds[r][c + 2] = v.z; Clds[r][c + 3] = v.w;
    const float4 wv = *(const float4*)(Wo + (h * 64 + r) * D_MODEL + cc * 64 + c);
    Wlds2[r][c] = wv.x; Wlds2[r][c + 1] = wv.y; Wlds2[r][c + 2] = wv.z; Wlds2[r][c + 3] = wv.w;
  }
  __syncthreads();
  float acc[4][4] = {};
#pragma unroll 8
  for (int k = 0; k < 64; ++k) {
    float a[4], wv[4];
#pragma unroll
    for (int i = 0; i < 4; ++i) a[i] = Clds[(ty << 2) + i][k];
#pragma unroll
    for (int j = 0; j < 4; ++j) wv[j] = Wlds2[k][(tx << 2) + j];
#pragma unroll
    for (int i = 0; i < 4; ++i)
#pragma unroll
      for (int j = 0; j < 4; ++j) acc[i][j] = fmaf(a[i], wv[j], acc[i][j]);
  }
#pragma unroll
  for (int i = 0; i < 4; ++i)
#pragma unroll
    for (int j = 0; j < 4; ++j) {
      const int c = cc * 64 + (tx << 2) + j;
      const int k = h * 64 + (ty << 2) + i;
      const int cb16 = c >> 4, lcc = c & 15;
      const int ksm = k >> 5, gg = (k >> 3) & 3, jb = k & 7;
      MTs[(size_t)b * 262144 + cb16 * 8192 + ksm * 512 + (gg * 16 + lcc) * 8 + jb]
          = f2bf(acc[i][j]);
    }
}

// ---------------- phase 3: [32][128] Q slices + softmax + out-GEMM ----------
__launch_bounds__(512, 2)
__global__ void phase3_kernel(const float* __restrict__ query, const u16* __restrict__ WTqs,
                              const float* __restrict__ bqp, const u16* __restrict__ MTs,
                              const float* __restrict__ bop, float* __restrict__ out) {
  __shared__ __align__(16) u16 smem[24576];  // 48KB
  u16* SL = smem;          // [2 buf][32 n][128 k], rows 256B, swz mask 7 (16KB)
  u16* P  = smem + 8192;   // [32 n][512 d], rows 1024B, swz mask 7 (32KB)
  const int t = threadIdx.x;
  const int lane = t & 63, w = t >> 6;
  const int g = lane >> 4, lc = lane & 15;
  const int chunk = blockIdx.x;
  const int n0 = chunk * 32;
  const int b = chunk >> 9;
  const int c0 = w * 64;
  const int sr = t >> 4;
  const int sc = t & 15;
  const int swoff = sr * 256 + ((sc * 16) ^ ((sr & 7) << 4));

  f32x4 acc[4][2];
#pragma unroll
  for (int m = 0; m < 4; ++m)
#pragma unroll
    for (int n = 0; n < 2; ++n) acc[m][n] = (f32x4){0.f, 0.f, 0.f, 0.f};

  float4 qreg[3][2];   // depth-3 rotating prefetch
  auto LOADQ = [&](int set, int gs) {
    const float* qp = query + (size_t)(n0 + sr) * D_MODEL + gs * 128 + sc * 8;
    qreg[set][0] = *(const float4*)qp; qreg[set][1] = *(const float4*)(qp + 4);
  };
  auto WRITEQ = [&](int set, int buf) {
    const float4 q0 = qreg[set][0], q1 = qreg[set][1];
    uint4 wq; wq.x = pk2(q0.x, q0.y); wq.y = pk2(q0.z, q0.w);
    wq.z = pk2(q1.x, q1.y); wq.w = pk2(q1.z, q1.w);
    *(uint4*)((char*)SL + buf * 8192 + swoff) = wq;
  };

  LOADQ(0, 0); LOADQ(1, 1); LOADQ(2, 2);
  WRITEQ(0, 0);
  bar_lgkm();

#pragma unroll
  for (int gs = 0; gs < 4; ++gs) {
    if (gs + 1 < 4) WRITEQ((gs + 1) % 3, (gs + 1) & 1);
    if (gs + 3 < 4) LOADQ(gs % 3, gs + 3);
    const u16* S = SL + (gs & 1) * 4096;
#pragma unroll
    for (int ksl = 0; ksl < 4; ++ksl) {
      const int ksm = gs * 4 + ksl;
      bf16x8 af[4], bfr[2];
#pragma unroll
      for (int mf = 0; mf < 4; ++mf)
        af[mf] = *(const bf16x8*)(WTqs + (w * 4 + mf) * 8192 + ksm * 512 + lane * 8);
      const int kb = ksl * 64 + g * 16;
#pragma unroll
      for (int nf = 0; nf < 2; ++nf) bfr[nf] = ldsrd(S, nf * 16 + lc, 256, kb, 7);
#pragma unroll
      for (int mf = 0; mf < 4; ++mf)
#pragma unroll
        for (int nf = 0; nf < 2; ++nf)
          acc[mf][nf] = __builtin_amdgcn_mfma_f32_16x16x32_bf16(af[mf], bfr[nf], acc[mf][nf], 0, 0, 0);
    }
    bar_lgkm();
  }
  // ---- softmax over d (per n), *1/8, bf16 -> P ----
  {
    float bqv[4][4];
#pragma unroll
    for (int m = 0; m < 4; ++m)
#pragma unroll
      for (int r = 0; r < 4; ++r) bqv[m][r] = bqp[c0 + m * 16 + g * 4 + r];
#pragma unroll
    for (int nf = 0; nf < 2; ++nf) {
      float mx = -3.0e38f;
#pragma unroll
      for (int m = 0; m < 4; ++m)
#pragma unroll
        for (int r = 0; r < 4; ++r) {
          const float v = acc[m][nf][r] + bqv[m][r];
          acc[m][nf][r] = v; mx = fmaxf(mx, v);
        }
      mx = fmaxf(mx, __shfl_xor(mx, 16)); mx = fmaxf(mx, __shfl_xor(mx, 32));
      float s = 0.f;
#pragma unroll
      for (int m = 0; m < 4; ++m)
#pragma unroll
        for (int r = 0; r < 4; ++r) {
          const float e = __expf(acc[m][nf][r] - mx);
          acc[m][nf][r] = e; s += e;
        }
      s += __shfl_xor(s, 16); s += __shfl_xor(s, 32);
      const float fsc = 0.125f / s;
      const int n = nf * 16 + lc;
#pragma unroll
      for (int m = 0; m < 4; ++m) {
        const uint2 pw = make_uint2(pk2(acc[m][nf][0] * fsc, acc[m][nf][1] * fsc),
                                    pk2(acc[m][nf][2] * fsc, acc[m][nf][3] * fsc));
        *(uint2*)((char*)P + n * 1024 + ((w * 128 + m * 32 + g * 8) ^ ((n & 7) << 4))) = pw;
      }
    }
  }
  bar_lgkm();
  // ---- out^T = Mbig^T[b] @ P^T ----
  f32x4 oc[4][2];
#pragma unroll
  for (int m = 0; m < 4; ++m)
#pragma unroll
    for (int n = 0; n < 2; ++n) oc[m][n] = (f32x4){0.f, 0.f, 0.f, 0.f};
  const u16* MT = MTs + (size_t)b * 262144;
#pragma unroll 2
  for (int ks = 0; ks < 16; ++ks) {
    bf16x8 af[4], bfr[2];
#pragma unroll
    for (int mf = 0; mf < 4; ++mf)
      af[mf] = *(const bf16x8*)(MT + (w * 4 + mf) * 8192 + ks * 512 + lane * 8);
#pragma unroll
    for (int nf = 0; nf < 2; ++nf) bfr[nf] = ldsrd(P, nf * 16 + lc, 1024, ks * 64 + g * 16, 7);
#pragma unroll
    for (int mf = 0; mf < 4; ++mf)
#pragma unroll
      for (int nf = 0; nf < 2; ++nf)
        oc[mf][nf] = __builtin_amdgcn_mfma_f32_16x16x32_bf16(af[mf], bfr[nf], oc[mf][nf], 0, 0, 0);
  }
  {
    float bov[4][4];
#pragma unroll
    for (int m = 0; m < 4; ++m)
#pragma unroll
      for (int r = 0; r < 4; ++r) bov[m][r] = bop[c0 + m * 16 + g * 4 + r];
#pragma unroll
    for (int mf = 0; mf < 4; ++mf)
#pragma unroll
      for (int nf = 0; nf < 2; ++nf) {
        float4 o;
        o.x = oc[mf][nf][0] + bov[mf][0]; o.y = oc[mf][nf][1] + bov[mf][1];
        o.z = oc[mf][nf][2] + bov[mf][2]; o.w = oc[mf][nf][3] + bov[mf][3];
        *(float4*)(out + (size_t)(n0 + nf * 16 + lc) * D_MODEL + c0 + mf * 16 + g * 4) = o;
      }
  }
}

__global__ void sentinel_kernel(float* out) { out[0] = 1.0e9f; }

extern "C" void kernel_launch(void* const* d_in, const int* in_sizes, int n_in,
                              void* d_out, int out_size, void* d_ws, size_t ws_size,
                              hipStream_t stream) {
  const float* query = (const float*)d_in[0];
  const float* key   = (const float*)d_in[1];
  const float* value = (const float*)d_in[2];
  const float* Wq = (const float*)d_in[3];
  const float* bq = (const float*)d_in[4];
  const float* Wk = (const float*)d_in[5];
  const float* bk = (const float*)d_in[6];
  const float* Wv = (const float*)d_in[7];
  const float* bv = (const float*)d_in[8];
  const float* Wo = (const float*)d_in[9];
  const float* bo = (const float*)d_in[10];
  float* out = (float*)d_out;
  char* ws = (char*)d_ws;

  if (ws_size < (size_t)WS_NEEDED) {
    sentinel_kernel<<<1, 1, 0, stream>>>(out);
    return;
  }

  float* part  = (float*)(ws + PART_OFF);
  float* sums  = (float*)(ws + SUMS_OFF);
  float* ctx   = (float*)(ws + CTX_OFF);
  u16* WTks    = (u16*)(ws + WTKS_OFF);
  u16* WTvs    = (u16*)(ws + WTVS_OFF);
  u16* WTqs    = (u16*)(ws + WTQS_OFF);
  u16* MTs     = (u16*)(ws + MTS_OFF);
  float* part2 = (float*)(ws + PART2_OFF);
  float* sums2 = (float*)(ws + SUMS2_OFF);

  const dim3 blk256(256);
  wcvt_kernel<<<dim3(8, 8, 3), blk256, 0, stream>>>(Wk, Wv, Wq, WTks, WTvs, WTqs);
  phase1_kernel<<<1024, 512, 0, stream>>>(key, value, WTks, WTvs, bk, bv, part, sums);
  reduce1_kernel<<<dim3(16, 16), blk256, 0, stream>>>(part, sums, part2, sums2);
  reduce2_kernel<<<16, blk256, 0, stream>>>(part2, sums2, ctx);
  mbigT_kernel<<<dim3(8, 16), blk256, 0, stream>>>(ctx, Wo, MTs);
  phase3_kernel<<<1024, 512, 0, stream>>>(query, WTqs, bq, MTs, bo, out);
}

// Round 18
// 200.955 us; speedup vs baseline: 1.1135x; 1.1135x over previous
//
#include <hip/hip_runtime.h>
#include <hip/hip_bf16.h>

// Linear attention (Shen 2018), B=2, N=16384, D=512, H=8, DK=64.
// Round 18 = consolidation: R16's phase1 (115us, VGPR 64, occ 40% — the
// in-register E^T experiment of R17 cost 16 VGPR and halved occupancy,
// reverted) + R17's two-stage reduce (kills the 16-CU serial tail).
// phase3/wcvt/mbigT unchanged (verified, absmax 1.9e-5).

using u16 = unsigned short;
typedef __attribute__((ext_vector_type(8))) short bf16x8;
typedef __attribute__((ext_vector_type(4))) float f32x4;

#define D_MODEL 512
#define SEQ 16384

// SWZ fragment layout for a 512x512 bf16 operand consumed as mfma_16x16x32
// row-panels: element (col,k) at cb16=col>>4, lc=col&15, ksm=k>>5, g=(k>>3)&3,
// j=k&7, lane=g*16+lc:  idx = cb16*8192 + ksm*512 + lane*8 + j   (u16 units)

// ---- ws layout (bytes) ----
#define PART_OFF 0u            // f32 [16 bh][128 grp][64 e][64 d] = 33,554,432
#define SUMS_OFF 33554432u     // f32 [16 bh][128 grp][64 d]       = 524,288
#define CTX_OFF  34078720u     // f32 [16][64 d][64 e]             = 262,144
#define WTKS_OFF 34340864u     // bf16 swz 512x512 = 524,288
#define WTVS_OFF 34865152u
#define WTQS_OFF 35389440u
#define MTS_OFF  35913728u     // bf16 swz [2]x512x512 = 1,048,576
#define PART2_OFF 36962304u    // f32 [16 bh][16 seg][4096] = 4,194,304
#define SUMS2_OFF 41156608u    // f32 [16 bh][16 seg][64]   = 65,536
#define WS_NEEDED 41222144u

__device__ __forceinline__ float bf2f(u16 u) {
  union { unsigned int i; float f; } x; x.i = ((unsigned int)u) << 16; return x.f;
}
__device__ __forceinline__ u16 f2bf(float f) {
  union { float ff; unsigned int i; } x; x.ff = f;
  unsigned int r = x.i + 0x7fffu + ((x.i >> 16) & 1u);  // RNE
  return (u16)(r >> 16);
}
__device__ __forceinline__ unsigned int pk2(float lo, float hi) {
  union { __hip_bfloat162 h; unsigned int u; } x;
  x.h = __float22bfloat162_rn(float2{lo, hi});
  return x.u;
}
__device__ __forceinline__ bf16x8 ldsrd(const u16* base, int row, int rowbytes,
                                        int kbyte, int mask) {
  return *(const bf16x8*)((const char*)base + row * rowbytes + (kbyte ^ ((row & mask) << 4)));
}
// LDS-only barrier (no vmcnt drain): safe because at every barrier the only
// in-flight vmem ops are register-destined loads or fire-and-forget stores.
__device__ __forceinline__ void bar_lgkm() {
  asm volatile("s_waitcnt lgkmcnt(0)" ::: "memory");
  __builtin_amdgcn_sched_barrier(0);
  __builtin_amdgcn_s_barrier();
  __builtin_amdgcn_sched_barrier(0);
}

// ------- transpose+convert W -> swizzled fragment-order bf16 panels ---------
__launch_bounds__(256)
__global__ void wcvt_kernel(const float* __restrict__ Wk, const float* __restrict__ Wv,
                            const float* __restrict__ Wq, u16* __restrict__ WTks,
                            u16* __restrict__ WTvs, u16* __restrict__ WTqs) {
  const float* in = blockIdx.z == 0 ? Wk : (blockIdx.z == 1 ? Wv : Wq);
  u16* out = blockIdx.z == 0 ? WTks : (blockIdx.z == 1 ? WTvs : WTqs);
  __shared__ float S[64][65];  // [k][col]
  const int t = threadIdx.x;
  const int k0 = blockIdx.y << 6, c0 = blockIdx.x << 6;
#pragma unroll
  for (int ii = 0; ii < 4; ++ii) {
    const int idx = t + ii * 256;
    const int r = idx >> 4, c4 = (idx & 15) << 2;
    const float4 v = *(const float4*)(in + (k0 + r) * D_MODEL + c0 + c4);
    S[r][c4] = v.x; S[r][c4 + 1] = v.y; S[r][c4 + 2] = v.z; S[r][c4 + 3] = v.w;
  }
  __syncthreads();
#pragma unroll
  for (int it = 0; it < 2; ++it) {
    const int fi = it * 256 + t;             // 0..511
    const int cb_loc = fi >> 7;              // 0..3
    const int ksm_loc = (fi >> 6) & 1;       // 0..1
    const int lane = fi & 63;
    const int col_loc = cb_loc * 16 + (lane & 15);
    const int kl0 = ksm_loc * 32 + (lane >> 4) * 8;
    union { bf16x8 v; u16 e[8]; } o;
#pragma unroll
    for (int jj = 0; jj < 8; ++jj) o.e[jj] = f2bf(S[kl0 + jj][col_loc]);
    const int cb16 = blockIdx.x * 4 + cb_loc;
    const int ksm = blockIdx.y * 2 + ksm_loc;
    *(bf16x8*)(out + cb16 * 8192 + ksm * 512 + lane * 8) = o.v;
  }
}

// ---------------- phase 1: [32][128] slices, depth-3 prefetch (R16) ---------
// grid 1024: xc=f&7 (XCD), k=f>>3: rowgroup = xc*32 + (k>>2) in [0,256),
// hp = k&3. Block: 8 waves = 2 heads (hloc=w>>2) x 4 col-quarters (cq=w&3);
// 16 slices of [32 rows][128 k] (4 chunks x 4), double-buffered LDS,
// 3 rotating register prefetch sets.
__launch_bounds__(512, 2)
__global__ void phase1_kernel(const float* __restrict__ key, const float* __restrict__ value,
                              const u16* __restrict__ WTks, const u16* __restrict__ WTvs,
                              const float* __restrict__ bkp, const float* __restrict__ bvp,
                              float* __restrict__ part, float* __restrict__ sums) {
  __shared__ __align__(16) u16 smem[24576];  // 48KB
  u16* KA = smem;            // [2 buf][32 n][128 k], rows 256B, swz mask 7 (16KB)
  u16* VA = smem + 8192;     // (16KB)
  u16* ET = smem + 16384;    // [2 hloc][64 d][32 n], rows 64B, swz mask 3 (8KB)
  u16* VT = smem + 20480;    // (8KB)
  const int t = threadIdx.x;
  const int lane = t & 63, w = t >> 6;
  const int g = lane >> 4, lc = lane & 15;
  const int f = blockIdx.x;
  const int xc = f & 7, kk2 = f >> 3;
  const int rowgroup = xc * 32 + (kk2 >> 2);   // 0..255
  const int hp = kk2 & 3;
  const int hloc = w >> 2, cq = w & 3;
  const int h = hp * 2 + hloc;
  const int dl = cq * 16 + lc;
  const int b = rowgroup >> 7, grpl = rowgroup & 127;
  const int bh = b * 8 + h;
  u16* ETh = ET + hloc * 2048;
  u16* VTh = VT + hloc * 2048;
  const u16* wtkb = WTks + (h * 4 + cq) * 8192;
  const u16* wtvb = WTvs + (h * 4 + cq) * 8192;
  const float bbk = bkp[h * 64 + dl];
  const float bbv = bvp[h * 64 + dl];
  const int sr = t >> 4;                 // staging row 0..31
  const int sc = t & 15;                 // staging col-octet (8 f32)
  const int swoff = sr * 256 + ((sc * 16) ^ ((sr & 7) << 4));

  f32x4 pacc[4];
#pragma unroll
  for (int em = 0; em < 4; ++em) pacc[em] = (f32x4){0.f, 0.f, 0.f, 0.f};
  float sp = 0.f;
  f32x4 aK0 = (f32x4){0.f,0.f,0.f,0.f}, aK1 = aK0, aV0 = aK0, aV1 = aK0;

  float4 kreg[3][2], vreg[3][2];   // depth-3 rotating prefetch sets
  auto LOADSL = [&](int set, int gs) {    // called with compile-time args
    const int row = (rowgroup * 4 + (gs >> 2)) * 32 + sr;
    const float* kp = key + (size_t)row * D_MODEL + (gs & 3) * 128 + sc * 8;
    kreg[set][0] = *(const float4*)kp; kreg[set][1] = *(const float4*)(kp + 4);
    const float* vp = value + (size_t)row * D_MODEL + (gs & 3) * 128 + sc * 8;
    vreg[set][0] = *(const float4*)vp; vreg[set][1] = *(const float4*)(vp + 4);
  };
  auto WRITESL = [&](int set, int buf) {
    const float4 k0 = kreg[set][0], k1 = kreg[set][1];
    uint4 wk; wk.x = pk2(k0.x, k0.y); wk.y = pk2(k0.z, k0.w);
    wk.z = pk2(k1.x, k1.y); wk.w = pk2(k1.z, k1.w);
    *(uint4*)((char*)KA + buf * 8192 + swoff) = wk;
    const float4 v0 = vreg[set][0], v1 = vreg[set][1];
    uint4 wv; wv.x = pk2(v0.x, v0.y); wv.y = pk2(v0.z, v0.w);
    wv.z = pk2(v1.x, v1.y); wv.w = pk2(v1.z, v1.w);
    *(uint4*)((char*)VA + buf * 8192 + swoff) = wv;
  };

  // prologue: slices 0,1,2 in flight; slice 0 -> buf0
  LOADSL(0, 0);
  LOADSL(1, 1);
  LOADSL(2, 2);
  WRITESL(0, 0);
  bar_lgkm();

#pragma unroll
  for (int gs = 0; gs < 16; ++gs) {
    // ---- B-frag panels for this slice (L2), issued first ----
    bf16x8 bK[4], bV[4];
#pragma unroll
    for (int j = 0; j < 4; ++j) {
      const int ksm = (gs & 3) * 4 + j;
      bK[j] = *(const bf16x8*)(wtkb + ksm * 512 + lane * 8);
      bV[j] = *(const bf16x8*)(wtvb + ksm * 512 + lane * 8);
    }
    // ---- write slice gs+1 (loaded 2 slice-periods ago: no vmcnt stall) ----
    if (gs + 1 < 16) WRITESL((gs + 1) % 3, (gs + 1) & 1);
    // ---- refill freed set with slice gs+3 ----
    if (gs + 3 < 16) LOADSL(gs % 3, gs + 3);
    const u16* bufK = KA + (gs & 1) * 4096;
    const u16* bufV = VA + (gs & 1) * 4096;
    // ---- 4 k-steps of MFMA on slice gs ----
#pragma unroll
    for (int ksl = 0; ksl < 4; ++ksl) {
      const int kb = ksl * 64 + g * 16;
      bf16x8 a0 = ldsrd(bufK, lc, 256, kb, 7);
      bf16x8 a1 = ldsrd(bufK, 16 + lc, 256, kb, 7);
      aK0 = __builtin_amdgcn_mfma_f32_16x16x32_bf16(a0, bK[ksl], aK0, 0, 0, 0);
      aK1 = __builtin_amdgcn_mfma_f32_16x16x32_bf16(a1, bK[ksl], aK1, 0, 0, 0);
      bf16x8 c0 = ldsrd(bufV, lc, 256, kb, 7);
      bf16x8 c1 = ldsrd(bufV, 16 + lc, 256, kb, 7);
      aV0 = __builtin_amdgcn_mfma_f32_16x16x32_bf16(c0, bV[ksl], aV0, 0, 0, 0);
      aV1 = __builtin_amdgcn_mfma_f32_16x16x32_bf16(c1, bV[ksl], aV1, 0, 0, 0);
    }
    if ((gs & 3) == 3) {
      // ---- chunk epilogue (byte-identical math to R16, verified) ----
#pragma unroll
      for (int r = 0; r < 4; ++r) { aK0[r] = __expf(aK0[r] + bbk); sp += aK0[r]; }
#pragma unroll
      for (int r = 0; r < 4; ++r) { aK1[r] = __expf(aK1[r] + bbk); sp += aK1[r]; }
      *(uint2*)((char*)ETh + dl * 64 + ((g * 8) ^ ((dl & 3) << 4))) =
          make_uint2(pk2(aK0[0], aK0[1]), pk2(aK0[2], aK0[3]));
      *(uint2*)((char*)ETh + dl * 64 + ((32 + g * 8) ^ ((dl & 3) << 4))) =
          make_uint2(pk2(aK1[0], aK1[1]), pk2(aK1[2], aK1[3]));
      *(uint2*)((char*)VTh + dl * 64 + ((g * 8) ^ ((dl & 3) << 4))) =
          make_uint2(pk2(aV0[0] + bbv, aV0[1] + bbv), pk2(aV0[2] + bbv, aV0[3] + bbv));
      *(uint2*)((char*)VTh + dl * 64 + ((32 + g * 8) ^ ((dl & 3) << 4))) =
          make_uint2(pk2(aV1[0] + bbv, aV1[1] + bbv), pk2(aV1[2] + bbv, aV1[3] + bbv));
      bar_lgkm();  // ET/VT complete across the head's 4 waves
      {
        bf16x8 paf = ldsrd(ETh, dl, 64, g * 16, 3);
#pragma unroll
        for (int em = 0; em < 4; ++em) {
          bf16x8 pbf = ldsrd(VTh, em * 16 + lc, 64, g * 16, 3);
          pacc[em] = __builtin_amdgcn_mfma_f32_16x16x32_bf16(paf, pbf, pacc[em], 0, 0, 0);
        }
      }
      aK0 = (f32x4){0.f,0.f,0.f,0.f}; aK1 = aK0; aV0 = aK0; aV1 = aK0;
    }
    bar_lgkm();  // slice gs+1 visible; buf (gs&1) reads done; epilogue's
                 // ET/VT reads done before the next chunk's epilogue writes.
  }

  // ---- one store per block: f32 partials [e][d] + colsums ----
  float* pp = part + (size_t)(bh * 128 + grpl) * 4096;
#pragma unroll
  for (int em = 0; em < 4; ++em)
    *(f32x4*)(pp + (em * 16 + lc) * 64 + cq * 16 + g * 4) = pacc[em];
  sp += __shfl_xor(sp, 16); sp += __shfl_xor(sp, 32);
  if (g == 0) sums[(size_t)(bh * 128 + grpl) * 64 + dl] = sp;
}

// ------- phase 2a: stage-1 reduce (256 blocks: 16 seg x 16 bh) --------------
__launch_bounds__(256)
__global__ void reduce1_kernel(const float* __restrict__ part, const float* __restrict__ sums,
                               float* __restrict__ part2, float* __restrict__ sums2) {
  const int seg = blockIdx.x, bh = blockIdx.y;
  const int t = threadIdx.x;
  float4 A0 = {0,0,0,0}, A1 = {0,0,0,0}, A2 = {0,0,0,0}, A3 = {0,0,0,0};
  const float* pb = part + (size_t)(bh * 128 + seg * 8) * 4096;
#pragma unroll
  for (int gp = 0; gp < 8; ++gp) {
    const float4* q = (const float4*)(pb + gp * 4096 + t * 16);
    const float4 q0 = q[0], q1 = q[1], q2 = q[2], q3 = q[3];
    A0.x += q0.x; A0.y += q0.y; A0.z += q0.z; A0.w += q0.w;
    A1.x += q1.x; A1.y += q1.y; A1.z += q1.z; A1.w += q1.w;
    A2.x += q2.x; A2.y += q2.y; A2.z += q2.z; A2.w += q2.w;
    A3.x += q3.x; A3.y += q3.y; A3.z += q3.z; A3.w += q3.w;
  }
  float4* o = (float4*)(part2 + (size_t)(bh * 16 + seg) * 4096 + t * 16);
  o[0] = A0; o[1] = A1; o[2] = A2; o[3] = A3;
  if (t < 64) {
    const float* sb = sums + (size_t)(bh * 128 + seg * 8) * 64 + t;
    float s = 0.f;
#pragma unroll
    for (int gp = 0; gp < 8; ++gp) s += sb[gp * 64];
    sums2[(size_t)(bh * 16 + seg) * 64 + t] = s;
  }
}

// ------- phase 2b: stage-2 reduce + normalize -> ctx[d][e] ------------------
__launch_bounds__(256)
__global__ void reduce2_kernel(const float* __restrict__ part2, const float* __restrict__ sums2,
                               float* __restrict__ ctx) {
  __shared__ float den[64];
  const int bh = blockIdx.x;
  const int t = threadIdx.x;
  if (t < 64) {
    const float* sb = sums2 + (size_t)bh * 16 * 64 + t;
    float s = 0.f;
#pragma unroll
    for (int seg = 0; seg < 16; ++seg) s += sb[seg * 64];
    den[t] = s;
  }
  float4 A0 = {0,0,0,0}, A1 = {0,0,0,0}, A2 = {0,0,0,0}, A3 = {0,0,0,0};
  const float* pb = part2 + (size_t)bh * 16 * 4096;
#pragma unroll
  for (int seg = 0; seg < 16; ++seg) {
    const float4* q = (const float4*)(pb + seg * 4096 + t * 16);
    const float4 q0 = q[0], q1 = q[1], q2 = q[2], q3 = q[3];
    A0.x += q0.x; A0.y += q0.y; A0.z += q0.z; A0.w += q0.w;
    A1.x += q1.x; A1.y += q1.y; A1.z += q1.z; A1.w += q1.w;
    A2.x += q2.x; A2.y += q2.y; A2.z += q2.z; A2.w += q2.w;
    A3.x += q3.x; A3.y += q3.y; A3.z += q3.z; A3.w += q3.w;
  }
  __syncthreads();
  // positions p = t*16 + i in [e][d]: e = t>>2, d = (t&3)*16 + i
  const int e = t >> 2, d0 = (t & 3) * 16;
  float* cb = ctx + (size_t)bh * 4096 + e;
  const float r0[4] = {A0.x, A0.y, A0.z, A0.w};
  const float r1[4] = {A1.x, A1.y, A1.z, A1.w};
  const float r2[4] = {A2.x, A2.y, A2.z, A2.w};
  const float r3[4] = {A3.x, A3.y, A3.z, A3.w};
#pragma unroll
  for (int i = 0; i < 4; ++i) cb[(d0 + i) * 64] = r0[i] / den[d0 + i];
#pragma unroll
  for (int i = 0; i < 4; ++i) cb[(d0 + 4 + i) * 64] = r1[i] / den[d0 + 4 + i];
#pragma unroll
  for (int i = 0; i < 4; ++i) cb[(d0 + 8 + i) * 64] = r2[i] / den[d0 + 8 + i];
#pragma unroll
  for (int i = 0; i < 4; ++i) cb[(d0 + 12 + i) * 64] = r3[i] / den[d0 + 12 + i];
}

// -------- MTs (swizzled) = (ctx_h @ Wo_h)^T per batch -----------------------
__launch_bounds__(256)
__global__ void mbigT_kernel(const float* __restrict__ ctx, const float* __restrict__ Wo,
                             u16* __restrict__ MTs) {
  __shared__ float Clds[64][65];
  __shared__ float Wlds2[64][64];
  const int t = threadIdx.x;
  const int tx = t & 15, ty = t >> 4;
  const int cc = blockIdx.x;
  const int bh = blockIdx.y;
  const int b = bh >> 3, h = bh & 7;
  const float* ch = ctx + bh * 4096;
  for (int i4 = t; i4 < 1024; i4 += 256) {
    const int r = i4 >> 4, c = (i4 & 15) << 2;
    const float4 v = *(const float4*)(ch + (r << 6) + c);
    Clds[r][c] = v.x; Clds[r][c + 1] = v.y; Clds[r][c + 2] = v.z; Clds[r][c + 3] = v.w;
    const float4 wv = *(const float4*)(Wo + (h * 64 + r) * D_MODEL + cc * 64 + c);
    Wlds2[r][c] = wv.x; Wlds2[r][c + 1] = wv.y; Wlds2[r][c + 2] = wv.z; Wlds2[r][c + 3] = wv.w;
  }
  __syncthreads();
  float acc[4][4] = {};
#pragma unroll 8
  for (int k = 0; k < 64; ++k) {
    float a[4], wv[4];
#pragma unroll
    for (int i = 0; i < 4; ++i) a[i] = Clds[(ty << 2) + i][k];
#pragma unroll
    for (int j = 0; j < 4; ++j) wv[j] = Wlds2[k][(tx << 2) + j];
#pragma unroll
    for (int i = 0; i < 4; ++i)
#pragma unroll
      for (int j = 0; j < 4; ++j) acc[i][j] = fmaf(a[i], wv[j], acc[i][j]);
  }
#pragma unroll
  for (int i = 0; i < 4; ++i)
#pragma unroll
    for (int j = 0; j < 4; ++j) {
      const int c = cc * 64 + (tx << 2) + j;
      const int k = h * 64 + (ty << 2) + i;
      const int cb16 = c >> 4, lcc = c & 15;
      const int ksm = k >> 5, gg = (k >> 3) & 3, jb = k & 7;
      MTs[(size_t)b * 262144 + cb16 * 8192 + ksm * 512 + (gg * 16 + lcc) * 8 + jb]
          = f2bf(acc[i][j]);
    }
}

// ---------------- phase 3: [32][128] Q slices + softmax + out-GEMM ----------
__launch_bounds__(512, 2)
__global__ void phase3_kernel(const float* __restrict__ query, const u16* __restrict__ WTqs,
                              const float* __restrict__ bqp, const u16* __restrict__ MTs,
                              const float* __restrict__ bop, float* __restrict__ out) {
  __shared__ __align__(16) u16 smem[24576];  // 48KB
  u16* SL = smem;          // [2 buf][32 n][128 k], rows 256B, swz mask 7 (16KB)
  u16* P  = smem + 8192;   // [32 n][512 d], rows 1024B, swz mask 7 (32KB)
  const int t = threadIdx.x;
  const int lane = t & 63, w = t >> 6;
  const int g = lane >> 4, lc = lane & 15;
  const int chunk = blockIdx.x;
  const int n0 = chunk * 32;
  const int b = chunk >> 9;
  const int c0 = w * 64;
  const int sr = t >> 4;
  const int sc = t & 15;
  const int swoff = sr * 256 + ((sc * 16) ^ ((sr & 7) << 4));

  f32x4 acc[4][2];
#pragma unroll
  for (int m = 0; m < 4; ++m)
#pragma unroll
    for (int n = 0; n < 2; ++n) acc[m][n] = (f32x4){0.f, 0.f, 0.f, 0.f};

  float4 qreg[3][2];   // depth-3 rotating prefetch
  auto LOADQ = [&](int set, int gs) {
    const float* qp = query + (size_t)(n0 + sr) * D_MODEL + gs * 128 + sc * 8;
    qreg[set][0] = *(const float4*)qp; qreg[set][1] = *(const float4*)(qp + 4);
  };
  auto WRITEQ = [&](int set, int buf) {
    const float4 q0 = qreg[set][0], q1 = qreg[set][1];
    uint4 wq; wq.x = pk2(q0.x, q0.y); wq.y = pk2(q0.z, q0.w);
    wq.z = pk2(q1.x, q1.y); wq.w = pk2(q1.z, q1.w);
    *(uint4*)((char*)SL + buf * 8192 + swoff) = wq;
  };

  LOADQ(0, 0); LOADQ(1, 1); LOADQ(2, 2);
  WRITEQ(0, 0);
  bar_lgkm();

#pragma unroll
  for (int gs = 0; gs < 4; ++gs) {
    if (gs + 1 < 4) WRITEQ((gs + 1) % 3, (gs + 1) & 1);
    if (gs + 3 < 4) LOADQ(gs % 3, gs + 3);
    const u16* S = SL + (gs & 1) * 4096;
#pragma unroll
    for (int ksl = 0; ksl < 4; ++ksl) {
      const int ksm = gs * 4 + ksl;
      bf16x8 af[4], bfr[2];
#pragma unroll
      for (int mf = 0; mf < 4; ++mf)
        af[mf] = *(const bf16x8*)(WTqs + (w * 4 + mf) * 8192 + ksm * 512 + lane * 8);
      const int kb = ksl * 64 + g * 16;
#pragma unroll
      for (int nf = 0; nf < 2; ++nf) bfr[nf] = ldsrd(S, nf * 16 + lc, 256, kb, 7);
#pragma unroll
      for (int mf = 0; mf < 4; ++mf)
#pragma unroll
        for (int nf = 0; nf < 2; ++nf)
          acc[mf][nf] = __builtin_amdgcn_mfma_f32_16x16x32_bf16(af[mf], bfr[nf], acc[mf][nf], 0, 0, 0);
    }
    bar_lgkm();
  }
  // ---- softmax over d (per n), *1/8, bf16 -> P ----
  {
    float bqv[4][4];
#pragma unroll
    for (int m = 0; m < 4; ++m)
#pragma unroll
      for (int r = 0; r < 4; ++r) bqv[m][r] = bqp[c0 + m * 16 + g * 4 + r];
#pragma unroll
    for (int nf = 0; nf < 2; ++nf) {
      float mx = -3.0e38f;
#pragma unroll
      for (int m = 0; m < 4; ++m)
#pragma unroll
        for (int r = 0; r < 4; ++r) {
          const float v = acc[m][nf][r] + bqv[m][r];
          acc[m][nf][r] = v; mx = fmaxf(mx, v);
        }
      mx = fmaxf(mx, __shfl_xor(mx, 16)); mx = fmaxf(mx, __shfl_xor(mx, 32));
      float s = 0.f;
#pragma unroll
      for (int m = 0; m < 4; ++m)
#pragma unroll
        for (int r = 0; r < 4; ++r) {
          const float e = __expf(acc[m][nf][r] - mx);
          acc[m][nf][r] = e; s += e;
        }
      s += __shfl_xor(s, 16); s += __shfl_xor(s, 32);
      const float fsc = 0.125f / s;
      const int n = nf * 16 + lc;
#pragma unroll
      for (int m = 0; m < 4; ++m) {
        const uint2 pw = make_uint2(pk2(acc[m][nf][0] * fsc, acc[m][nf][1] * fsc),
                                    pk2(acc[m][nf][2] * fsc, acc[m][nf][3] * fsc));
        *(uint2*)((char*)P + n * 1024 + ((w * 128 + m * 32 + g * 8) ^ ((n & 7) << 4))) = pw;
      }
    }
  }
  bar_lgkm();
  // ---- out^T = Mbig^T[b] @ P^T ----
  f32x4 oc[4][2];
#pragma unroll
  for (int m = 0; m < 4; ++m)
#pragma unroll
    for (int n = 0; n < 2; ++n) oc[m][n] = (f32x4){0.f, 0.f, 0.f, 0.f};
  const u16* MT = MTs + (size_t)b * 262144;
#pragma unroll 2
  for (int ks = 0; ks < 16; ++ks) {
    bf16x8 af[4], bfr[2];
#pragma unroll
    for (int mf = 0; mf < 4; ++mf)
      af[mf] = *(const bf16x8*)(MT + (w * 4 + mf) * 8192 + ks * 512 + lane * 8);
#pragma unroll
    for (int nf = 0; nf < 2; ++nf) bfr[nf] = ldsrd(P, nf * 16 + lc, 1024, ks * 64 + g * 16, 7);
#pragma unroll
    for (int mf = 0; mf < 4; ++mf)
#pragma unroll
      for (int nf = 0; nf < 2; ++nf)
        oc[mf][nf] = __builtin_amdgcn_mfma_f32_16x16x32_bf16(af[mf], bfr[nf], oc[mf][nf], 0, 0, 0);
  }
  {
    float bov[4][4];
#pragma unroll
    for (int m = 0; m < 4; ++m)
#pragma unroll
      for (int r = 0; r < 4; ++r) bov[m][r] = bop[c0 + m * 16 + g * 4 + r];
#pragma unroll
    for (int mf = 0; mf < 4; ++mf)
#pragma unroll
      for (int nf = 0; nf < 2; ++nf) {
        float4 o;
        o.x = oc[mf][nf][0] + bov[mf][0]; o.y = oc[mf][nf][1] + bov[mf][1];
        o.z = oc[mf][nf][2] + bov[mf][2]; o.w = oc[mf][nf][3] + bov[mf][3];
        *(float4*)(out + (size_t)(n0 + nf * 16 + lc) * D_MODEL + c0 + mf * 16 + g * 4) = o;
      }
  }
}

__global__ void sentinel_kernel(float* out) { out[0] = 1.0e9f; }

extern "C" void kernel_launch(void* const* d_in, const int* in_sizes, int n_in,
                              void* d_out, int out_size, void* d_ws, size_t ws_size,
                              hipStream_t stream) {
  const float* query = (const float*)d_in[0];
  const float* key   = (const float*)d_in[1];
  const float* value = (const float*)d_in[2];
  const float* Wq = (const float*)d_in[3];
  const float* bq = (const float*)d_in[4];
  const float* Wk = (const float*)d_in[5];
  const float* bk = (const float*)d_in[6];
  const float* Wv = (const float*)d_in[7];
  const float* bv = (const float*)d_in[8];
  const float* Wo = (const float*)d_in[9];
  const float* bo = (const float*)d_in[10];
  float* out = (float*)d_out;
  char* ws = (char*)d_ws;

  if (ws_size < (size_t)WS_NEEDED) {
    sentinel_kernel<<<1, 1, 0, stream>>>(out);
    return;
  }

  float* part  = (float*)(ws + PART_OFF);
  float* sums  = (float*)(ws + SUMS_OFF);
  float* ctx   = (float*)(ws + CTX_OFF);
  u16* WTks    = (u16*)(ws + WTKS_OFF);
  u16* WTvs    = (u16*)(ws + WTVS_OFF);
  u16* WTqs    = (u16*)(ws + WTQS_OFF);
  u16* MTs     = (u16*)(ws + MTS_OFF);
  float* part2 = (float*)(ws + PART2_OFF);
  float* sums2 = (float*)(ws + SUMS2_OFF);

  const dim3 blk256(256);
  wcvt_kernel<<<dim3(8, 8, 3), blk256, 0, stream>>>(Wk, Wv, Wq, WTks, WTvs, WTqs);
  phase1_kernel<<<1024, 512, 0, stream>>>(key, value, WTks, WTvs, bk, bv, part, sums);
  reduce1_kernel<<<dim3(16, 16), blk256, 0, stream>>>(part, sums, part2, sums2);
  reduce2_kernel<<<16, blk256, 0, stream>>>(part2, sums2, ctx);
  mbigT_kernel<<<dim3(8, 16), blk256, 0, stream>>>(ctx, Wo, MTs);
  phase3_kernel<<<1024, 512, 0, stream>>>(query, WTqs, bq, MTs, bo, out);
}